// Round 8
// baseline (328.628 us; speedup 1.0000x reference)
//
#include <hip/hip_runtime.h>
#include <stdint.h>

typedef unsigned short u16;
typedef __attribute__((ext_vector_type(8))) __bf16 bf16x8;
typedef __attribute__((ext_vector_type(4))) float f32x4;

// ---------- helpers ----------
__device__ __forceinline__ u16 f2bf(float f) {  // RNE fp32 -> bf16
  unsigned int u = __builtin_bit_cast(unsigned int, f);
  u = (u + 0x7FFFu + ((u >> 16) & 1u)) >> 16;
  return (u16)u;
}
__device__ __forceinline__ u16 tern2bf(int s) {
  return s == 0 ? (u16)0 : (s > 0 ? (u16)0x3F80 : (u16)0xBF80);
}

#define GLOAD_LDS16(g, l)                                                          \
  __builtin_amdgcn_global_load_lds((__attribute__((address_space(1))) void*)(g),   \
                                   (__attribute__((address_space(3))) void*)(l),   \
                                   16, 0, 0)

// ---------- problem sizes ----------
#define M_TOK 8192
#define N_OUT 4096
#define K_IN  4096
#define RANK  32

// ---------- ws layout (bytes) ----------
#define WS_XB    0ull
#define WS_WB    67108864ull
#define WS_BB    100663296ull
#define WS_A32   100925440ull
#define WS_T32   101187584ull
#define WS_TPART 101711872ull
#define WS_FLAG  110100480ull

// ---------- prep kernels ----------
__global__ void k_convert_x(const float4* __restrict__ x, ushort4* __restrict__ xb, int n4) {
  int stride = gridDim.x * blockDim.x;
  for (int i = blockIdx.x * blockDim.x + threadIdx.x; i < n4; i += stride) {
    float4 v = x[i];
    ushort4 o;
    o.x = f2bf(v.x); o.y = f2bf(v.y); o.z = f2bf(v.z); o.w = f2bf(v.w);
    xb[i] = o;
  }
}

__global__ void k_detect_wtype(const int* __restrict__ w, int* __restrict__ flag) {
  int v = w[threadIdx.x];
  bool ok = (v >= -1 && v <= 1);
  unsigned long long m = __ballot(ok);
  if (threadIdx.x == 0) *flag = (m == ~0ull) ? 1 : 0;
}

__global__ void k_convert_w(const void* __restrict__ wq, const int* __restrict__ flag,
                            ushort4* __restrict__ wb, int n4) {
  int is32 = *flag;
  int stride = gridDim.x * blockDim.x;
  for (int i = blockIdx.x * blockDim.x + threadIdx.x; i < n4; i += stride) {
    int s0, s1, s2, s3;
    if (is32) {
      int4 c = ((const int4*)wq)[i];
      s0 = c.x; s1 = c.y; s2 = c.z; s3 = c.w;
    } else {
      char4 c = ((const char4*)wq)[i];
      s0 = c.x; s1 = c.y; s2 = c.z; s3 = c.w;
    }
    ushort4 o;
    o.x = tern2bf(s0); o.y = tern2bf(s1); o.z = tern2bf(s2); o.w = tern2bf(s3);
    wb[i] = o;
  }
}

__global__ void k_prep_B(const float* __restrict__ loraB, u16* __restrict__ bb) {
  int idx = blockIdx.x * blockDim.x + threadIdx.x;
  if (idx < RANK * K_IN) bb[idx] = f2bf(loraB[idx]);
}

__global__ void k_prep_A(const float* __restrict__ loraA, const float* __restrict__ scale,
                         u16* __restrict__ a32) {
  int idx = blockIdx.x * blockDim.x + threadIdx.x;
  if (idx >= N_OUT * RANK) return;
  int o = idx >> 5;
  a32[idx] = f2bf(loraA[idx] / scale[o]);
}

// ---------- T = x @ B^T (partials over 8 K-slices) ----------
__global__ __launch_bounds__(256) void k_lora_T(const u16* __restrict__ xb,
                                                const u16* __restrict__ bb,
                                                float* __restrict__ tpart) {
  __shared__ u16 As[256 * 32];
  __shared__ u16 Bs[32 * 32];
  int mt = blockIdx.x >> 3;
  int ks = blockIdx.x & 7;
  int tid = threadIdx.x, lane = tid & 63, wave = tid >> 6;
  int m0 = mt * 256;
  int kbase0 = ks * 512;
  f32x4 acc[4][2] = {};
  for (int step = 0; step < 16; ++step) {
    int kb = kbase0 + step * 32;
    __syncthreads();
#pragma unroll
    for (int i = 0; i < 4; ++i) {
      const u16* src = xb + (size_t)(m0 + i * 64 + (tid >> 2)) * K_IN + kb + (tid & 3) * 8;
      GLOAD_LDS16(src, &As[i * 2048 + tid * 8]);
    }
    if (tid < 128) {
      const u16* src = bb + (size_t)(tid >> 2) * K_IN + kb + (tid & 3) * 8;
      GLOAD_LDS16(src, &Bs[tid * 8]);
    }
    __syncthreads();
    bf16x8 b[2];
#pragma unroll
    for (int ni = 0; ni < 2; ++ni)
      b[ni] = *(const bf16x8*)&Bs[(ni * 16 + (lane & 15)) * 32 + (lane >> 4) * 8];
#pragma unroll
    for (int mi = 0; mi < 4; ++mi) {
      bf16x8 a = *(const bf16x8*)&As[(wave * 64 + mi * 16 + (lane & 15)) * 32 + (lane >> 4) * 8];
      acc[mi][0] = __builtin_amdgcn_mfma_f32_16x16x32_bf16(a, b[0], acc[mi][0], 0, 0, 0);
      acc[mi][1] = __builtin_amdgcn_mfma_f32_16x16x32_bf16(a, b[1], acc[mi][1], 0, 0, 0);
    }
  }
#pragma unroll
  for (int mi = 0; mi < 4; ++mi)
#pragma unroll
    for (int ni = 0; ni < 2; ++ni)
#pragma unroll
      for (int r = 0; r < 4; ++r) {
        int row = m0 + wave * 64 + mi * 16 + (lane >> 4) * 4 + r;
        int col = ni * 16 + (lane & 15);
        tpart[((size_t)ks * M_TOK + row) * RANK + col] = acc[mi][ni][r];
      }
}

__global__ void k_reduce_T(const float* __restrict__ tpart, u16* __restrict__ t32) {
  int idx = blockIdx.x * blockDim.x + threadIdx.x;
  if (idx >= M_TOK * RANK) return;
  int t = idx >> 5, r = idx & 31;
  float v = 0.f;
#pragma unroll
  for (int s = 0; s < 8; ++s) v += tpart[((size_t)s * M_TOK + t) * RANK + r];
  t32[idx] = f2bf(v);
}

// ---------- main GEMM: 256x256, BK=32, ring-4 LDS, interleaved burst ----------
// R7 skeleton (0-conflict swizzle, W4 + 1 barrier/tile, full-tile register
// read-ahead) with the MFMA burst and next-tile ds_reads INTERLEAVED per wave:
// {8 MFMA, 2 ds_read}x3 + {8 MFMA, 6 ds_read}, pinned via sched_group_barrier,
// so the LDS pipe (~1150 cyc/tile/CU) runs concurrently with the MFMA pipe
// (~1242 cyc/SIMD) instead of serializing. Frag regs reloaded only after
// their last consumer (fa0 after g0/g1, fa1 after g2/g3, fb after g3).
// Sync structure (proven R6/R7): W4 => per-wave stages <=t+2 landed;
// BARR(t-1) makes tile t+1 globally landed before any read of slot t+1.
__global__ __launch_bounds__(512, 2) void k_gemm8(const u16* __restrict__ xb,
                                                  const u16* __restrict__ wb,
                                                  const u16* __restrict__ t32,
                                                  const u16* __restrict__ a32,
                                                  const float* __restrict__ scale,
                                                  const float* __restrict__ bias,
                                                  float* __restrict__ out) {
  __shared__ u16 As[4][8192];  // 4 slots x 16KB
  __shared__ u16 Bs[4][8192];
  const int tid = threadIdx.x;
  const int l = tid & 63, w = tid >> 6;
  const int wm = w >> 2, wn = w & 3;
  const int bid = blockIdx.x;
  const int swz = (bid & 7) * 64 + (bid >> 3);
  const int m0 = (swz >> 4) * 256, n0 = (swz & 15) * 256;

  const int srow0 = (w * 2 + 0) * 16 + (l >> 2);
  const int srow1 = (w * 2 + 1) * 16 + (l >> 2);
  const int scx = ((l & 3) ^ ((l >> 3) & 3)) * 8;
  const int ldst0 = (w * 2 + 0) * 512 + l * 8;
  const int ldst1 = (w * 2 + 1) * 512 + l * 8;
  const int r15 = l & 15;
  const int cxr = (((l >> 4) ^ ((r15 >> 1) & 3)) * 8);

  f32x4 acc[8][4] = {};

  u16* AsF = &As[0][0];
  u16* BsF = &Bs[0][0];
  const u16* axs0 = xb + (size_t)(m0 + srow0) * K_IN + scx;
  const u16* axs1 = xb + (size_t)(m0 + srow1) * K_IN + scx;
  const u16* bxs0 = wb + (size_t)(n0 + srow0) * K_IN + scx;
  const u16* bxs1 = wb + (size_t)(n0 + srow1) * K_IN + scx;

  // prologue: stage tiles 0,1,2
#pragma unroll
  for (int ts = 0; ts < 3; ++ts) {
    GLOAD_LDS16(axs0 + ts * 32, AsF + ts * 8192 + ldst0);
    GLOAD_LDS16(axs1 + ts * 32, AsF + ts * 8192 + ldst1);
    GLOAD_LDS16(bxs0 + ts * 32, BsF + ts * 8192 + ldst0);
    GLOAD_LDS16(bxs1 + ts * 32, BsF + ts * 8192 + ldst1);
  }
  asm volatile("s_waitcnt vmcnt(4)" ::: "memory");  // tiles 0,1 landed (this wave)
  asm volatile("s_barrier" ::: "memory");           // => landed cross-wave

  const int abase = (wm * 128 + r15) * 32 + cxr;
  const int bbase = (wn * 64 + r15) * 32 + cxr;

  // running stage pointers -> tile 3
  const u16* ap0 = axs0 + 96;
  const u16* ap1 = axs1 + 96;
  const u16* bp0 = bxs0 + 96;
  const u16* bp1 = bxs1 + 96;

  bf16x8 fa0[4], fa1[4], fb[4];  // single frag set, rewritten each tile

#define SA(DST)                                                                     \
  { GLOAD_LDS16(ap0, AsF + (DST) * 8192 + ldst0);                                   \
    GLOAD_LDS16(ap1, AsF + (DST) * 8192 + ldst1);                                   \
    ap0 += 32; ap1 += 32; }
#define SB(DST)                                                                     \
  { GLOAD_LDS16(bp0, BsF + (DST) * 8192 + ldst0);                                   \
    GLOAD_LDS16(bp1, BsF + (DST) * 8192 + ldst1);                                   \
    bp0 += 32; bp1 += 32; }
#define W4  asm volatile("s_waitcnt vmcnt(4)" ::: "memory");
#define W0  asm volatile("s_waitcnt vmcnt(0)" ::: "memory");
#define BARR asm volatile("s_barrier" ::: "memory");
#define MM0(mi, nj)                                                                 \
  acc[mi][nj] = __builtin_amdgcn_mfma_f32_16x16x32_bf16(fa0[mi], fb[nj], acc[mi][nj], 0, 0, 0);
#define MM1(mi, nj)                                                                 \
  acc[4 + (mi)][nj] =                                                               \
      __builtin_amdgcn_mfma_f32_16x16x32_bf16(fa1[mi], fb[nj], acc[4 + (mi)][nj], 0, 0, 0);
#define SGB(M, N) __builtin_amdgcn_sched_group_barrier(M, N, 0);
#define READN(NS)                                                                   \
  { const u16* An = AsF + (NS) * 8192;                                              \
    const u16* Bn = BsF + (NS) * 8192;                                              \
    _Pragma("unroll") for (int mi = 0; mi < 4; ++mi)                                \
        fa0[mi] = *(const bf16x8*)&An[abase + mi * 512];                            \
    _Pragma("unroll") for (int mi = 0; mi < 4; ++mi)                                \
        fa1[mi] = *(const bf16x8*)&An[abase + 2048 + mi * 512];                     \
    _Pragma("unroll") for (int nj = 0; nj < 4; ++nj)                                \
        fb[nj] = *(const bf16x8*)&Bn[bbase + nj * 512]; }

// Interleaved tile: reads of slot NS woven into the 32-MFMA burst.
#define TILE(NS, STAGE, WAIT, BAR)                                                  \
  {                                                                                 \
    const u16* An = AsF + (NS) * 8192;                                              \
    const u16* Bn = BsF + (NS) * 8192;                                              \
    STAGE                                                                           \
    __builtin_amdgcn_s_setprio(1);                                                  \
    MM0(0, 0) MM0(0, 1) MM0(0, 2) MM0(0, 3) MM0(1, 0) MM0(1, 1) MM0(1, 2) MM0(1, 3) \
    fa0[0] = *(const bf16x8*)&An[abase + 0 * 512];                                  \
    fa0[1] = *(const bf16x8*)&An[abase + 1 * 512];                                  \
    MM0(2, 0) MM0(2, 1) MM0(2, 2) MM0(2, 3) MM0(3, 0) MM0(3, 1) MM0(3, 2) MM0(3, 3) \
    fa0[2] = *(const bf16x8*)&An[abase + 2 * 512];                                  \
    fa0[3] = *(const bf16x8*)&An[abase + 3 * 512];                                  \
    MM1(0, 0) MM1(0, 1) MM1(0, 2) MM1(0, 3) MM1(1, 0) MM1(1, 1) MM1(1, 2) MM1(1, 3) \
    fa1[0] = *(const bf16x8*)&An[abase + 2048 + 0 * 512];                           \
    fa1[1] = *(const bf16x8*)&An[abase + 2048 + 1 * 512];                           \
    MM1(2, 0) MM1(2, 1) MM1(2, 2) MM1(2, 3) MM1(3, 0) MM1(3, 1) MM1(3, 2) MM1(3, 3) \
    fa1[2] = *(const bf16x8*)&An[abase + 2048 + 2 * 512];                           \
    fa1[3] = *(const bf16x8*)&An[abase + 2048 + 3 * 512];                           \
    fb[0] = *(const bf16x8*)&Bn[bbase + 0 * 512];                                   \
    fb[1] = *(const bf16x8*)&Bn[bbase + 1 * 512];                                   \
    fb[2] = *(const bf16x8*)&Bn[bbase + 2 * 512];                                   \
    fb[3] = *(const bf16x8*)&Bn[bbase + 3 * 512];                                   \
    __builtin_amdgcn_s_setprio(0);                                                  \
    SGB(0x8, 8) SGB(0x100, 2)                                                       \
    SGB(0x8, 8) SGB(0x100, 2)                                                       \
    SGB(0x8, 8) SGB(0x100, 2)                                                       \
    SGB(0x8, 8) SGB(0x100, 6)                                                       \
    WAIT                                                                            \
    BAR                                                                             \
  }

// Final tile: no reads, pure burst.
#define TILEF                                                                       \
  {                                                                                 \
    __builtin_amdgcn_s_setprio(1);                                                  \
    MM0(0, 0) MM0(0, 1) MM0(0, 2) MM0(0, 3) MM0(1, 0) MM0(1, 1) MM0(1, 2) MM0(1, 3) \
    MM0(2, 0) MM0(2, 1) MM0(2, 2) MM0(2, 3) MM0(3, 0) MM0(3, 1) MM0(3, 2) MM0(3, 3) \
    MM1(0, 0) MM1(0, 1) MM1(0, 2) MM1(0, 3) MM1(1, 0) MM1(1, 1) MM1(1, 2) MM1(1, 3) \
    MM1(2, 0) MM1(2, 1) MM1(2, 2) MM1(2, 3) MM1(3, 0) MM1(3, 1) MM1(3, 2) MM1(3, 3) \
    __builtin_amdgcn_s_setprio(0);                                                  \
  }

  READN(0)  // tile 0 frags (post-prologue-barrier: globally landed)

  // main loop: tiles 0..123, staging 3..127
#pragma unroll 1
  for (int t = 0; t < 124; t += 4) {
    TILE(1, SA(3) SB(3), W4, BARR)
    TILE(2, SA(0) SB(0), W4, BARR)
    TILE(3, SA(1) SB(1), W4, BARR)
    TILE(0, SA(2) SB(2), W4, BARR)
  }
  // t=124: stage tile 127 -> slot 3; reads slot 1 (tile 125)
  TILE(1, SA(3) SB(3), W4, BARR)
  // t=125: stage LoRA tile (128) -> slot 0; reads slot 2 (tile 126)
  {
    const u16* la0 = t32 + (size_t)(m0 + srow0) * RANK + scx;
    const u16* la1 = t32 + (size_t)(m0 + srow1) * RANK + scx;
    const u16* lb0 = a32 + (size_t)(n0 + srow0) * RANK + scx;
    const u16* lb1 = a32 + (size_t)(n0 + srow1) * RANK + scx;
    TILE(2,
         { GLOAD_LDS16(la0, AsF + 0 * 8192 + ldst0); GLOAD_LDS16(la1, AsF + 0 * 8192 + ldst1);
           GLOAD_LDS16(lb0, BsF + 0 * 8192 + ldst0); GLOAD_LDS16(lb1, BsF + 0 * 8192 + ldst1); },
         W4, BARR)
  }
  // t=126: full drain so LoRA slot is globally landed after this barrier
  TILE(3, , W0, BARR)
  // t=127: reads LoRA frags (slot 0)
  TILE(0, , , BARR)
  // t=128: LoRA tile, frags preloaded
  TILEF

  // epilogue: out = acc*scale[col] + bias[col]
#pragma unroll
  for (int nj = 0; nj < 4; ++nj) {
    int col = n0 + wn * 64 + nj * 16 + r15;
    float s = scale[col], bv = bias[col];
#pragma unroll
    for (int fi = 0; fi < 8; ++fi) {
      int row = m0 + wm * 128 + (fi >> 2) * 64 + (fi & 3) * 16 + (l >> 4) * 4;
#pragma unroll
      for (int r = 0; r < 4; ++r)
        out[(size_t)(row + r) * N_OUT + col] = acc[fi][nj][r] * s + bv;
    }
  }
}

// ---------- launch ----------
extern "C" void kernel_launch(void* const* d_in, const int* in_sizes, int n_in,
                              void* d_out, int out_size, void* d_ws, size_t ws_size,
                              hipStream_t stream) {
  const float* x     = (const float*)d_in[0];
  const void*  wq    = d_in[1];
  const float* scale = (const float*)d_in[2];
  const float* loraA = (const float*)d_in[3];
  const float* loraB = (const float*)d_in[4];
  const float* bias  = (const float*)d_in[5];
  float* out = (float*)d_out;

  char* ws = (char*)d_ws;
  u16*   xb    = (u16*)(ws + WS_XB);
  u16*   wbuf  = (u16*)(ws + WS_WB);
  u16*   bb    = (u16*)(ws + WS_BB);
  u16*   a32   = (u16*)(ws + WS_A32);
  u16*   t32   = (u16*)(ws + WS_T32);
  float* tpart = (float*)(ws + WS_TPART);
  int*   flag  = (int*)(ws + WS_FLAG);

  k_convert_x<<<2048, 256, 0, stream>>>((const float4*)x, (ushort4*)xb, M_TOK * K_IN / 4);
  k_detect_wtype<<<1, 64, 0, stream>>>((const int*)wq, flag);
  k_convert_w<<<2048, 256, 0, stream>>>(wq, flag, (ushort4*)wbuf, N_OUT * K_IN / 4);
  k_prep_B<<<512, 256, 0, stream>>>(loraB, bb);
  k_prep_A<<<512, 256, 0, stream>>>(loraA, scale, a32);
  k_lora_T<<<256, 256, 0, stream>>>(xb, bb, tpart);
  k_reduce_T<<<1024, 256, 0, stream>>>(tpart, t32);
  k_gemm8<<<512, 512, 0, stream>>>(xb, wbuf, t32, a32, scale, bias, out);

  (void)in_sizes; (void)n_in; (void)out_size; (void)ws_size;
}